// Round 3
// baseline (2365.092 us; speedup 1.0000x reference)
//
#include <hip/hip_runtime.h>
#include <math.h>

typedef __bf16 bf16_t;
typedef bf16_t bf16x8 __attribute__((ext_vector_type(8)));
typedef float  f32x4  __attribute__((ext_vector_type(4)));

#define N_NODES 20000
#define NEDGE   320000
#define DIM     128
#define TP      136           // LDS row stride (elems): 272B, 16B aligned, 2-way bank aliasing (free)
#define EBLK    2500          // NEDGE / 128

// ---- WF (MFMA b-frag-layout weights, bf16) offsets; each 128x128 chunk = 16384 elems ----
// chunk layout: [kk 0..3][ct 0..7][lane 0..63][j 0..7] ; value = W[kc*128 + kk*32 + (lane>>4)*8 + j][ct*16 + (lane&15)]
#define FE1  0                // 3 chunks (x_row, x_col, edge_attr parts of W_e1)
#define FE2  49152            // 1 chunk
#define FM1  65536            // 2 chunks
#define FM2  98304            // 1 chunk
#define FU1  114688           // 3 chunks
#define FU2  163840           // 1 chunk
#define FK   180224           // 1 chunk
#define FV   196608           // 1 chunk
#define WF_ELEMS 212992       // 13 * 16384

// ---------------- shared helpers ----------------
__device__ __forceinline__ void acc_zero(f32x4 acc[2][8]) {
  f32x4 z = {0.f, 0.f, 0.f, 0.f};
#pragma unroll
  for (int i = 0; i < 2; ++i)
#pragma unroll
    for (int j = 0; j < 8; ++j) acc[i][j] = z;
}

// ---- staging: 128 rows x 128 cols into bf16 LDS tile (stride TP) ----
__device__ __forceinline__ void stage_rows_bf(bf16_t* dst, const bf16_t* src, const int* rows, int t) {
#pragma unroll
  for (int i = 0; i < 8; ++i) {
    int c = t + i * 256;
    int r = c >> 4, off = (c & 15) * 8;
    *(uint4*)(dst + r * TP + off) = *(const uint4*)(src + (size_t)rows[r] * DIM + off);
  }
}

__device__ __forceinline__ void stage_rows_f32(bf16_t* dst, const float* src, const int* rows, int t) {
#pragma unroll
  for (int i = 0; i < 8; ++i) {
    int c = t + i * 256;
    int r = c >> 4, off = (c & 15) * 8;
    const float* sp = src + (size_t)rows[r] * DIM + off;
    float4 f0 = *(const float4*)sp;
    float4 f1 = *(const float4*)(sp + 4);
    bf16x8 tv;
    tv[0]=(bf16_t)f0.x; tv[1]=(bf16_t)f0.y; tv[2]=(bf16_t)f0.z; tv[3]=(bf16_t)f0.w;
    tv[4]=(bf16_t)f1.x; tv[5]=(bf16_t)f1.y; tv[6]=(bf16_t)f1.z; tv[7]=(bf16_t)f1.w;
    *(bf16x8*)(dst + r * TP + off) = tv;
  }
}

__device__ __forceinline__ void stage_seq_bf(bf16_t* dst, const bf16_t* src, int base, int nvalid, int t) {
#pragma unroll
  for (int i = 0; i < 8; ++i) {
    int c = t + i * 256;
    int r = c >> 4, off = (c & 15) * 8;
    uint4 v = make_uint4(0u, 0u, 0u, 0u);
    if (r < nvalid) v = *(const uint4*)(src + (size_t)(base + r) * DIM + off);
    *(uint4*)(dst + r * TP + off) = v;
  }
}

__device__ __forceinline__ void stage_seq_f32(bf16_t* dst, const float* src, int base, int nvalid, int t) {
#pragma unroll
  for (int i = 0; i < 8; ++i) {
    int c = t + i * 256;
    int r = c >> 4, off = (c & 15) * 8;
    bf16x8 tv;
    if (r < nvalid) {
      const float* sp = src + (size_t)(base + r) * DIM + off;
      float4 f0 = *(const float4*)sp;
      float4 f1 = *(const float4*)(sp + 4);
      tv[0]=(bf16_t)f0.x; tv[1]=(bf16_t)f0.y; tv[2]=(bf16_t)f0.z; tv[3]=(bf16_t)f0.w;
      tv[4]=(bf16_t)f1.x; tv[5]=(bf16_t)f1.y; tv[6]=(bf16_t)f1.z; tv[7]=(bf16_t)f1.w;
    } else {
#pragma unroll
      for (int j = 0; j < 8; ++j) tv[j] = (bf16_t)0.f;
    }
    *(bf16x8*)(dst + r * TP + off) = tv;
  }
}

// one K=128 MFMA pass: A from LDS (wave-private 32 rows), B-frags streamed from global WF chunk
__device__ __forceinline__ void mfma_gk128(const bf16_t* A, const bf16_t* __restrict__ Wf,
                                           int w, int lane, int lm, int lq, f32x4 acc[2][8]) {
#pragma unroll
  for (int kk = 0; kk < 4; ++kk) {
    int ko = kk * 32 + lq * 8;
    bf16x8 a0 = *(const bf16x8*)(A + (w * 32 + lm) * TP + ko);
    bf16x8 a1 = *(const bf16x8*)(A + (w * 32 + 16 + lm) * TP + ko);
    const bf16_t* wp = Wf + ((kk * 8) << 9) + (lane << 3);
#pragma unroll
    for (int ct = 0; ct < 8; ++ct) {
      bf16x8 bfr = *(const bf16x8*)(wp + (ct << 9));
      acc[0][ct] = __builtin_amdgcn_mfma_f32_16x16x32_bf16(a0, bfr, acc[0][ct], 0, 0, 0);
      acc[1][ct] = __builtin_amdgcn_mfma_f32_16x16x32_bf16(a1, bfr, acc[1][ct], 0, 0, 0);
    }
  }
}

// ---------------- prep kernels ----------------
// build b-frag-layout bf16 weights from f32 sources. 13 chunks of 16384 elems.
__global__ void gn_fragw(const float* We1, const float* We2, const float* Wm1, const float* Wm2,
                         const float* Wu1, const float* Wu2, const float* Wk, const float* Wv,
                         bf16_t* WF) {
  int idx = blockIdx.x * 256 + threadIdx.x;
  if (idx >= WF_ELEMS) return;
  int seg = idx >> 14;
  const float* W; int kc;
  switch (seg) {
    case 0:  W = We1; kc = 0; break;
    case 1:  W = We1; kc = 1; break;
    case 2:  W = We1; kc = 2; break;
    case 3:  W = We2; kc = 0; break;
    case 4:  W = Wm1; kc = 0; break;
    case 5:  W = Wm1; kc = 1; break;
    case 6:  W = Wm2; kc = 0; break;
    case 7:  W = Wu1; kc = 0; break;
    case 8:  W = Wu1; kc = 1; break;
    case 9:  W = Wu1; kc = 2; break;
    case 10: W = Wu2; kc = 0; break;
    case 11: W = Wk;  kc = 0; break;
    default: W = Wv;  kc = 0; break;
  }
  int r = idx & 16383;
  int j = r & 7, lane = (r >> 3) & 63, ct = (r >> 9) & 7, kk = (r >> 12) & 3;
  int k = kc * 128 + kk * 32 + (lane >> 4) * 8 + j;
  int n = ct * 16 + (lane & 15);
  WF[idx] = (bf16_t)W[k * 128 + n];
}

// R = u @ W_e1[384:512] + b_e1 ; uw = u @ W_w[128:256] + b_w
__global__ void gn_uprep(const float* u, const float* We1, const float* be1,
                         const float* Ww, const float* bw, float* R, float* uw) {
  int t = threadIdx.x;
  for (int idx = blockIdx.x * 256 + t; idx < 32 * 128; idx += gridDim.x * 256) {
    int g = idx >> 7, c = idx & 127;
    float acc = be1[c];
    for (int k = 0; k < 128; ++k) acc += u[g * 128 + k] * We1[(384 + k) * 128 + c];
    R[idx] = acc;
  }
  if (blockIdx.x == 0 && t < 32) {
    float acc = bw[0];
    for (int k = 0; k < 128; ++k) acc += u[t * 128 + k] * Ww[128 + k];
    uw[t] = acc;
  }
}

__global__ void gn_count(const int* ei, float* cnt) {
  int e = blockIdx.x * 256 + threadIdx.x;
  if (e < NEDGE) atomicAdd(&cnt[ei[NEDGE + e]], 1.0f);
}

__global__ void gn_q(const float* qa, const float* Wq, const float* bq, float* qb) {
  int b = blockIdx.x, t = threadIdx.x;
  int c = t & 127, half = t >> 7;
  const float* qrow = qa + b * 1024 + half * 512;
  float acc = 0.f;
  for (int k = 0; k < 512; ++k) acc += qrow[k] * Wq[(half * 512 + k) * 128 + c];
  __shared__ float red[256];
  red[t] = acc;
  __syncthreads();
  if (half == 0) qb[b * 128 + c] = red[c] + red[128 + c] + bq[c];
}

// ---------------- edge kernel (EdgeModel + wt logits) ----------------
__global__ __launch_bounds__(256) void gn_edge(
    const void* xsrcv, const void* esrcv, int first, bf16_t* edst,
    const bf16_t* __restrict__ WF,
    const float* R, const float* uwv, const float* Ww, const float* be2,
    const int* ei, const int* nbat,
    float* wl, float* pm, float* ps) {
  __shared__ bf16_t sA[128 * TP];
  __shared__ int lrow[128], lcol[128], lg[128];
  __shared__ float lwt[128], lwv[128];

  int t = threadIdx.x, blk = blockIdx.x;
  int e0 = blk * 128;
  int w = t >> 6, lane = t & 63, lm = lane & 15, lq = lane >> 4;

  if (t < 128) {
    int e = e0 + t;
    int r = ei[e];
    lrow[t] = r;
    lcol[t] = ei[NEDGE + e];
    lg[t]   = nbat[r];
    lwv[t]  = Ww[t];
  }
  __syncthreads();

  f32x4 acc[2][8];
  acc_zero(acc);

  // chunk 0: x[row]
  if (first) stage_rows_f32(sA, (const float*)xsrcv, lrow, t);
  else       stage_rows_bf (sA, (const bf16_t*)xsrcv, lrow, t);
  __syncthreads();
  mfma_gk128(sA, WF + FE1, w, lane, lm, lq, acc);
  __syncthreads();
  // chunk 1: x[col]
  if (first) stage_rows_f32(sA, (const float*)xsrcv, lcol, t);
  else       stage_rows_bf (sA, (const bf16_t*)xsrcv, lcol, t);
  __syncthreads();
  mfma_gk128(sA, WF + FE1 + 16384, w, lane, lm, lq, acc);
  __syncthreads();
  // chunk 2: old edge_attr
  if (first) stage_seq_f32(sA, (const float*)esrcv, e0, 128, t);
  else       stage_seq_bf (sA, (const bf16_t*)esrcv, e0, 128, t);
  __syncthreads();
  // wt logits from OLD edge_attr (2 threads / edge)
  {
    int er = t >> 1, th = t & 1;
    float s = 0.f;
    const bf16_t* arow = sA + er * TP + th * 64;
#pragma unroll
    for (int jj = 0; jj < 8; ++jj) {
      bf16x8 av = *(const bf16x8*)(arow + jj * 8);
#pragma unroll
      for (int j = 0; j < 8; ++j) s += (float)av[j] * lwv[th * 64 + jj * 8 + j];
    }
    s += __shfl_xor(s, 1);
    if (th == 0) {
      float v = s + uwv[lg[er]];
      wl[e0 + er] = v;
      lwt[er] = v;
    }
  }
  mfma_gk128(sA, WF + FE1 + 32768, w, lane, lm, lq, acc);
  __syncthreads();

  // epilogue 1: + R[g] (includes b_e1), relu -> hidden into sA
#pragma unroll
  for (int rt = 0; rt < 2; ++rt)
#pragma unroll
    for (int reg = 0; reg < 4; ++reg) {
      int row = w * 32 + rt * 16 + lq * 4 + reg;
      const float* Rr = R + (size_t)lg[row] * DIM;
#pragma unroll
      for (int ct = 0; ct < 8; ++ct) {
        int col = ct * 16 + lm;
        float v = acc[rt][ct][reg] + Rr[col];
        sA[row * TP + col] = (bf16_t)fmaxf(v, 0.f);
      }
    }
  __syncthreads();

  acc_zero(acc);
  mfma_gk128(sA, WF + FE2, w, lane, lm, lq, acc);

  // epilogue 2: + b_e2, store new edge_attr (bf16 internal)
#pragma unroll
  for (int rt = 0; rt < 2; ++rt)
#pragma unroll
    for (int reg = 0; reg < 4; ++reg) {
      int row = w * 32 + rt * 16 + lq * 4 + reg;
      bf16_t* drow = edst + (size_t)(e0 + row) * DIM;
#pragma unroll
      for (int ct = 0; ct < 8; ++ct) {
        int col = ct * 16 + lm;
        drow[col] = (bf16_t)(acc[rt][ct][reg] + be2[col]);
      }
    }

  // per-block (max, sumexp) partials per graph
  __syncthreads();
  if (t < 32) {
    float m = -1e30f;
    for (int i = 0; i < 128; ++i) if (lg[i] == t) m = fmaxf(m, lwt[i]);
    float sacc = 0.f;
    if (m > -1e29f)
      for (int i = 0; i < 128; ++i) if (lg[i] == t) sacc += expf(lwt[i] - m);
    pm[blk * 32 + t] = m;
    ps[blk * 32 + t] = sacc;
  }
}

__global__ void gn_reduce_ms(const float* pm, const float* ps, float* mg, float* sg, int nb) {
  int g = blockIdx.x, t = threadIdx.x;
  __shared__ float red[256];
  float m = -1e30f;
  for (int i = t; i < nb; i += 256) m = fmaxf(m, pm[i * 32 + g]);
  red[t] = m; __syncthreads();
  for (int s2 = 128; s2 > 0; s2 >>= 1) { if (t < s2) red[t] = fmaxf(red[t], red[t + s2]); __syncthreads(); }
  m = red[0]; __syncthreads();
  float s = 0.f;
  for (int i = t; i < nb; i += 256) {
    float sb = ps[i * 32 + g];
    if (sb > 0.f) s += sb * expf(pm[i * 32 + g] - m);
  }
  red[t] = s; __syncthreads();
  for (int s2 = 128; s2 > 0; s2 >>= 1) { if (t < s2) red[t] += red[t + s2]; __syncthreads(); }
  if (t == 0) { mg[g] = m; sg[g] = red[0]; }
}

// ---------------- message kernel (NodeModel msg + weighted scatter) ----------------
__global__ __launch_bounds__(256) void gn_msg(
    const void* xsrcv, int first, const bf16_t* ebuf,
    const bf16_t* __restrict__ WF,
    const float* bm1, const float* bm2,
    const float* wl, const float* mg, const float* sg,
    const int* ei, const int* nbat, float* recv) {
  __shared__ bf16_t sA[128 * TP];
  __shared__ int lrow[128], lcol[128], lg[128];
  __shared__ float lnw[128];

  int t = threadIdx.x, blk = blockIdx.x;
  int e0 = blk * 128;
  int w = t >> 6, lane = t & 63, lm = lane & 15, lq = lane >> 4;

  if (t < 128) {
    int e = e0 + t;
    int r = ei[e];
    lrow[t] = r;
    lcol[t] = ei[NEDGE + e];
    int g = nbat[r];
    lg[t] = g;
    lnw[t] = expf(wl[e] - mg[g]) / sg[g];
  }
  __syncthreads();

  f32x4 acc[2][8];
  acc_zero(acc);

  // chunk 0: x[row]
  if (first) stage_rows_f32(sA, (const float*)xsrcv, lrow, t);
  else       stage_rows_bf (sA, (const bf16_t*)xsrcv, lrow, t);
  __syncthreads();
  mfma_gk128(sA, WF + FM1, w, lane, lm, lq, acc);
  __syncthreads();
  // chunk 1: new edge_attr (contiguous, bf16)
  stage_seq_bf(sA, ebuf, e0, 128, t);
  __syncthreads();
  mfma_gk128(sA, WF + FM1 + 16384, w, lane, lm, lq, acc);
  __syncthreads();

  // epilogue1: + b_m1, relu -> hidden
#pragma unroll
  for (int rt = 0; rt < 2; ++rt)
#pragma unroll
    for (int reg = 0; reg < 4; ++reg) {
      int row = w * 32 + rt * 16 + lq * 4 + reg;
#pragma unroll
      for (int ct = 0; ct < 8; ++ct) {
        int col = ct * 16 + lm;
        float v = acc[rt][ct][reg] + bm1[col];
        sA[row * TP + col] = (bf16_t)fmaxf(v, 0.f);
      }
    }
  __syncthreads();

  acc_zero(acc);
  mfma_gk128(sA, WF + FM2, w, lane, lm, lq, acc);

  // epilogue2: msg = acc + b_m2 ; scatter msg*norm_w into recv[col]
#pragma unroll
  for (int rt = 0; rt < 2; ++rt)
#pragma unroll
    for (int reg = 0; reg < 4; ++reg) {
      int row = w * 32 + rt * 16 + lq * 4 + reg;
      float nwv = lnw[row];
      float* rr = recv + (size_t)lcol[row] * DIM;
#pragma unroll
      for (int ct = 0; ct < 8; ++ct) {
        int col = ct * 16 + lm;
        atomicAdd(&rr[col], (acc[rt][ct][reg] + bm2[col]) * nwv);
      }
    }
}

// ---------------- node update kernel ----------------
__global__ __launch_bounds__(256) void gn_node(
    const void* xsrcv, int first, bf16_t* xdst, const float* recv, const float* cnt,
    const float* u, const bf16_t* __restrict__ WF,
    const float* bu1, const float* bu2, const int* nbat) {
  __shared__ bf16_t sA[128 * TP];
  __shared__ int lg[128];

  int t = threadIdx.x;
  int n0 = blockIdx.x * 128;
  int nvalid = N_NODES - n0; if (nvalid > 128) nvalid = 128;
  int w = t >> 6, lane = t & 63, lm = lane & 15, lq = lane >> 4;

  if (t < 128) {
    int n = n0 + t;
    lg[t] = (t < nvalid) ? nbat[n] : 0;
  }
  __syncthreads();

  f32x4 acc[2][8];
  acc_zero(acc);

  // chunk 0: x (contiguous)
  if (first) stage_seq_f32(sA, (const float*)xsrcv, n0, nvalid, t);
  else       stage_seq_bf (sA, (const bf16_t*)xsrcv, n0, nvalid, t);
  __syncthreads();
  mfma_gk128(sA, WF + FU1, w, lane, lm, lq, acc);
  __syncthreads();
  // chunk 1: received = recv / max(cnt,1), converted to bf16
#pragma unroll
  for (int i = 0; i < 8; ++i) {
    int c = t + i * 256;
    int r = c >> 4, off = (c & 15) * 8;
    bf16x8 tv;
    if (r < nvalid) {
      const float* rr = recv + (size_t)(n0 + r) * DIM + off;
      float ic = 1.f / fmaxf(cnt[n0 + r], 1.f);
#pragma unroll
      for (int j = 0; j < 8; ++j) tv[j] = (bf16_t)(rr[j] * ic);
    } else {
#pragma unroll
      for (int j = 0; j < 8; ++j) tv[j] = (bf16_t)0.f;
    }
    *(bf16x8*)(sA + r * TP + off) = tv;
  }
  __syncthreads();
  mfma_gk128(sA, WF + FU1 + 16384, w, lane, lm, lq, acc);
  __syncthreads();
  // chunk 2: u[node_batch] (u is external f32 [32,128], L2-resident)
  stage_rows_f32(sA, u, lg, t);
  __syncthreads();
  mfma_gk128(sA, WF + FU1 + 32768, w, lane, lm, lq, acc);
  __syncthreads();

  // epilogue1: + b_u1, relu -> hidden
#pragma unroll
  for (int rt = 0; rt < 2; ++rt)
#pragma unroll
    for (int reg = 0; reg < 4; ++reg) {
      int row = w * 32 + rt * 16 + lq * 4 + reg;
#pragma unroll
      for (int ct = 0; ct < 8; ++ct) {
        int col = ct * 16 + lm;
        float v = acc[rt][ct][reg] + bu1[col];
        sA[row * TP + col] = (bf16_t)fmaxf(v, 0.f);
      }
    }
  __syncthreads();

  acc_zero(acc);
  mfma_gk128(sA, WF + FU2, w, lane, lm, lq, acc);

#pragma unroll
  for (int rt = 0; rt < 2; ++rt)
#pragma unroll
    for (int reg = 0; reg < 4; ++reg) {
      int row = w * 32 + rt * 16 + lq * 4 + reg;
      if (row < nvalid) {
        bf16_t* dr = xdst + (size_t)(n0 + row) * DIM;
#pragma unroll
        for (int ct = 0; ct < 8; ++ct) {
          int col = ct * 16 + lm;
          dr[col] = (bf16_t)(acc[rt][ct][reg] + bu2[col]);
        }
      }
    }
}

// ---------------- evidence -> K/V projection (reads internal bf16 XB) ----------------
__global__ __launch_bounds__(256) void gn_ev(
    const bf16_t* xsrc, const bf16_t* __restrict__ WF,
    const float* bk, const float* bv, float* kb, float* vb) {
  __shared__ bf16_t sA[128 * TP];

  int t = threadIdx.x;
  int n0 = blockIdx.x * 128;
  int nvalid = N_NODES - n0; if (nvalid > 128) nvalid = 128;
  int sel = blockIdx.y;
  const bf16_t* Wf = WF + (sel ? FV : FK);
  const float* bias = sel ? bv : bk;
  float* dst = sel ? vb : kb;
  int w = t >> 6, lane = t & 63, lm = lane & 15, lq = lane >> 4;

  // stage gelu(x) tile
#pragma unroll
  for (int i = 0; i < 8; ++i) {
    int c = t + i * 256;
    int r = c >> 4, off = (c & 15) * 8;
    bf16x8 tv;
    if (r < nvalid) {
      uint4 v = *(const uint4*)(xsrc + (size_t)(n0 + r) * DIM + off);
      bf16_t tmp[8];
      *(uint4*)tmp = v;
#pragma unroll
      for (int j = 0; j < 8; ++j) {
        float f = (float)tmp[j];
        tv[j] = (bf16_t)(0.5f * f * (1.f + erff(f * 0.70710678118654752f)));
      }
    } else {
#pragma unroll
      for (int j = 0; j < 8; ++j) tv[j] = (bf16_t)0.f;
    }
    *(bf16x8*)(sA + r * TP + off) = tv;
  }
  __syncthreads();

  f32x4 acc[2][8];
  acc_zero(acc);
  mfma_gk128(sA, Wf, w, lane, lm, lq, acc);

#pragma unroll
  for (int rt = 0; rt < 2; ++rt)
#pragma unroll
    for (int reg = 0; reg < 4; ++reg) {
      int row = w * 32 + rt * 16 + lq * 4 + reg;
      if (row < nvalid) {
        float* dr = dst + (size_t)(n0 + row) * DIM;
#pragma unroll
        for (int ct = 0; ct < 8; ++ct) {
          int col = ct * 16 + lm;
          dr[col] = acc[rt][ct][reg] + bias[col];
        }
      }
    }
}

// ---------------- pooled edge (final layer) ----------------
__global__ void gn_pooled_edge(const bf16_t* eb, const float* wl, const float* mg, const float* sg,
                               const int* ei, const int* nbat, float* pe) {
  __shared__ float loc[4096];
  int t = threadIdx.x;
  for (int i = t; i < 4096; i += 256) loc[i] = 0.f;
  __syncthreads();
  for (int idx = blockIdx.x * 256 + t; idx < NEDGE * 64; idx += gridDim.x * 256) {
    int e = idx >> 6, sub = idx & 63;
    int g = nbat[ei[e]];
    float nw = expf(wl[e] - mg[g]) / sg[g];
    const bf16_t* er = eb + (size_t)e * DIM + sub * 2;
    atomicAdd(&loc[g * 128 + sub * 2],     (float)er[0] * nw);
    atomicAdd(&loc[g * 128 + sub * 2 + 1], (float)er[1] * nw);
  }
  __syncthreads();
  for (int i = t; i < 4096; i += 256) atomicAdd(&pe[i], loc[i]);
}

// ---------------- attention pool ----------------
__global__ void gn_att(const float* qb, const float* kb, const float* vb, const int* non, float* out) {
  int b = blockIdx.x >> 1, h = blockIdx.x & 1, t = threadIdx.x;
  __shared__ float qv[64];
  __shared__ float sc[625];
  __shared__ float red[256];
  if (t < 64) qv[t] = qb[b * 128 + h * 64 + t];
  __syncthreads();
  int nn = non[b];
  for (int l = t; l < 625; l += 256) {
    float acc = 0.f;
    const float* kr = kb + ((size_t)(b * 625 + l)) * DIM + h * 64;
    for (int d2 = 0; d2 < 64; ++d2) acc += qv[d2] * kr[d2];
    sc[l] = (l < nn) ? acc * 0.125f : -1e30f;
  }
  __syncthreads();
  float m = -1e30f;
  for (int l = t; l < 625; l += 256) m = fmaxf(m, sc[l]);
  red[t] = m; __syncthreads();
  for (int s2 = 128; s2 > 0; s2 >>= 1) { if (t < s2) red[t] = fmaxf(red[t], red[t + s2]); __syncthreads(); }
  m = red[0]; __syncthreads();
  float ssum = 0.f;
  for (int l = t; l < 625; l += 256) { float e = expf(sc[l] - m); sc[l] = e; ssum += e; }
  red[t] = ssum; __syncthreads();
  for (int s2 = 128; s2 > 0; s2 >>= 1) { if (t < s2) red[t] += red[t + s2]; __syncthreads(); }
  float inv = 1.f / red[0];
  __syncthreads();
  int d = t & 63, seg = t >> 6;
  float acc = 0.f;
  for (int l = seg; l < 625; l += 4) acc += sc[l] * vb[((size_t)(b * 625 + l)) * DIM + h * 64 + d];
  red[t] = acc; __syncthreads();
  if (t < 64) {
    float v = red[t] + red[64 + t] + red[128 + t] + red[192 + t];
    out[b * 256 + 128 + h * 64 + d] = v * inv;
  }
}

__global__ void gn_fin(const float* pe, float* out) {
  int t = threadIdx.x;
  for (int i = t; i < 4096; i += 256) {
    int b = i >> 7, c = i & 127;
    out[b * 256 + c] = pe[i];
  }
}

// ---------------- launcher ----------------
extern "C" void kernel_launch(void* const* d_in, const int* in_sizes, int n_in,
                              void* d_out, int out_size, void* d_ws, size_t ws_size,
                              hipStream_t stream) {
  const float* x   = (const float*)d_in[0];
  const float* ea  = (const float*)d_in[1];
  const float* u   = (const float*)d_in[2];
  const float* qa  = (const float*)d_in[3];
  const float* We1 = (const float*)d_in[4];
  const float* be1 = (const float*)d_in[5];
  const float* We2 = (const float*)d_in[6];
  const float* be2 = (const float*)d_in[7];
  const float* Ww  = (const float*)d_in[8];
  const float* bw  = (const float*)d_in[9];
  const float* Wm1 = (const float*)d_in[10];
  const float* bm1 = (const float*)d_in[11];
  const float* Wm2 = (const float*)d_in[12];
  const float* bm2 = (const float*)d_in[13];
  const float* Wu1 = (const float*)d_in[14];
  const float* bu1 = (const float*)d_in[15];
  const float* Wu2 = (const float*)d_in[16];
  const float* bu2 = (const float*)d_in[17];
  const float* Wq  = (const float*)d_in[18];
  const float* bq  = (const float*)d_in[19];
  const float* Wk  = (const float*)d_in[20];
  const float* bk  = (const float*)d_in[21];
  const float* Wv  = (const float*)d_in[22];
  const float* bv  = (const float*)d_in[23];
  const int* ei   = (const int*)d_in[24];
  const int* nbat = (const int*)d_in[25];
  const int* non  = (const int*)d_in[26];
  float* out = (float*)d_out;

  char* p = (char*)d_ws;
  auto alloc = [&](size_t bytes) { char* r = p; p += (bytes + 255) & ~(size_t)255; return r; };
  bf16_t* EB  = (bf16_t*)alloc((size_t)NEDGE * DIM * 2);
  bf16_t* XB  = (bf16_t*)alloc((size_t)N_NODES * DIM * 2);
  float* RECV = (float*)alloc((size_t)N_NODES * DIM * 4);
  float* CNT  = (float*)alloc((size_t)N_NODES * 4);
  float* WL   = (float*)alloc((size_t)NEDGE * 4);
  float* PM   = (float*)alloc((size_t)EBLK * 32 * 4);
  float* PS   = (float*)alloc((size_t)EBLK * 32 * 4);
  float* MG   = (float*)alloc(32 * 4);
  float* SG   = (float*)alloc(32 * 4);
  float* R    = (float*)alloc(32 * 128 * 4);
  float* UW   = (float*)alloc(32 * 4);
  bf16_t* WF  = (bf16_t*)alloc((size_t)WF_ELEMS * 2);
  float* QB   = (float*)alloc(32 * 128 * 4);
  float* KB   = (float*)alloc((size_t)N_NODES * DIM * 4);
  float* VB   = (float*)alloc((size_t)N_NODES * DIM * 4);
  float* PE   = (float*)alloc(32 * 128 * 4);

  hipMemsetAsync(CNT, 0, (size_t)N_NODES * 4, stream);
  hipMemsetAsync(PE, 0, 32 * 128 * 4, stream);

  gn_fragw<<<(WF_ELEMS + 255) / 256, 256, 0, stream>>>(We1, We2, Wm1, Wm2, Wu1, Wu2, Wk, Wv, WF);
  gn_uprep<<<16, 256, 0, stream>>>(u, We1, be1, Ww, bw, R, UW);
  gn_count<<<1250, 256, 0, stream>>>(ei, CNT);
  gn_q<<<32, 256, 0, stream>>>(qa, Wq, bq, QB);

  for (int layer = 0; layer < 3; ++layer) {
    int first = (layer == 0) ? 1 : 0;
    const void* xs = first ? (const void*)x : (const void*)XB;
    const void* es = first ? (const void*)ea : (const void*)EB;
    gn_edge<<<EBLK, 256, 0, stream>>>(xs, es, first, EB, WF, R, UW, Ww, be2, ei, nbat, WL, PM, PS);
    gn_reduce_ms<<<32, 256, 0, stream>>>(PM, PS, MG, SG, EBLK);
    hipMemsetAsync(RECV, 0, (size_t)N_NODES * DIM * 4, stream);
    gn_msg<<<EBLK, 256, 0, stream>>>(xs, first, EB, WF, bm1, bm2, WL, MG, SG, ei, nbat, RECV);
    gn_node<<<157, 256, 0, stream>>>(xs, first, XB, RECV, CNT, u, WF, bu1, bu2, nbat);
  }

  gn_pooled_edge<<<256, 256, 0, stream>>>(EB, WL, MG, SG, ei, nbat, PE);
  gn_ev<<<dim3(157, 2), 256, 0, stream>>>(XB, WF, bk, bv, KB, VB);
  gn_att<<<64, 256, 0, stream>>>(QB, KB, VB, non, out);
  gn_fin<<<1, 256, 0, stream>>>(PE, out);
}

// Round 4
// 1698.217 us; speedup vs baseline: 1.3927x; 1.3927x over previous
//
#include <hip/hip_runtime.h>
#include <math.h>

typedef __bf16 bf16_t;
typedef bf16_t bf16x8 __attribute__((ext_vector_type(8)));
typedef bf16_t bf16x4 __attribute__((ext_vector_type(4)));
typedef float  f32x4  __attribute__((ext_vector_type(4)));

#define N_NODES 20000
#define NEDGE   320000
#define DIM     128
#define TP      136           // LDS row stride (elems): 272B, 16B aligned, 2-way bank aliasing (free)
#define EBLK    2500          // NEDGE / 128

// ---- WF (MFMA b-frag-layout weights, bf16) offsets; each 128x128 chunk = 16384 elems ----
// chunk layout: [kk 0..3][ct 0..7][lane 0..63][j 0..7] ; value = W[kc*128 + kk*32 + (lane>>4)*8 + j][ct*16 + (lane&15)]
#define FE1  0                // 3 chunks (x_row, x_col, edge_attr parts of W_e1)
#define FE2  49152            // 1 chunk
#define FM1  65536            // 2 chunks (x_row, new_edge parts of W_m1)
#define FM2  98304            // 1 chunk
#define FU1  114688           // 3 chunks
#define FU2  163840           // 1 chunk
#define FK   180224           // 1 chunk
#define FV   196608           // 1 chunk
#define WF_ELEMS 212992       // 13 * 16384

// ---------------- shared helpers ----------------
__device__ __forceinline__ void acc_zero(f32x4 acc[2][8]) {
  f32x4 z = {0.f, 0.f, 0.f, 0.f};
#pragma unroll
  for (int i = 0; i < 2; ++i)
#pragma unroll
    for (int j = 0; j < 8; ++j) acc[i][j] = z;
}

// stage 128 rows x 128 cols (bf16) gathered by row-index table in LDS
__device__ __forceinline__ void stage_rows_bf(bf16_t* dst, const bf16_t* src, const int* rows, int t) {
#pragma unroll
  for (int i = 0; i < 8; ++i) {
    int c = t + i * 256;
    int r = c >> 4, off = (c & 15) * 8;
    *(uint4*)(dst + r * TP + off) = *(const uint4*)(src + (size_t)rows[r] * DIM + off);
  }
}

__device__ __forceinline__ void stage_rows_f32(bf16_t* dst, const float* src, const int* rows, int t) {
#pragma unroll
  for (int i = 0; i < 8; ++i) {
    int c = t + i * 256;
    int r = c >> 4, off = (c & 15) * 8;
    const float* sp = src + (size_t)rows[r] * DIM + off;
    float4 f0 = *(const float4*)sp;
    float4 f1 = *(const float4*)(sp + 4);
    bf16x8 tv;
    tv[0]=(bf16_t)f0.x; tv[1]=(bf16_t)f0.y; tv[2]=(bf16_t)f0.z; tv[3]=(bf16_t)f0.w;
    tv[4]=(bf16_t)f1.x; tv[5]=(bf16_t)f1.y; tv[6]=(bf16_t)f1.z; tv[7]=(bf16_t)f1.w;
    *(bf16x8*)(dst + r * TP + off) = tv;
  }
}

__device__ __forceinline__ void stage_seq_bf(bf16_t* dst, const bf16_t* src, int base, int nvalid, int t) {
#pragma unroll
  for (int i = 0; i < 8; ++i) {
    int c = t + i * 256;
    int r = c >> 4, off = (c & 15) * 8;
    uint4 v = make_uint4(0u, 0u, 0u, 0u);
    if (r < nvalid) v = *(const uint4*)(src + (size_t)(base + r) * DIM + off);
    *(uint4*)(dst + r * TP + off) = v;
  }
}

__device__ __forceinline__ void stage_seq_f32(bf16_t* dst, const float* src, int base, int nvalid, int t) {
#pragma unroll
  for (int i = 0; i < 8; ++i) {
    int c = t + i * 256;
    int r = c >> 4, off = (c & 15) * 8;
    bf16x8 tv;
    if (r < nvalid) {
      const float* sp = src + (size_t)(base + r) * DIM + off;
      float4 f0 = *(const float4*)sp;
      float4 f1 = *(const float4*)(sp + 4);
      tv[0]=(bf16_t)f0.x; tv[1]=(bf16_t)f0.y; tv[2]=(bf16_t)f0.z; tv[3]=(bf16_t)f0.w;
      tv[4]=(bf16_t)f1.x; tv[5]=(bf16_t)f1.y; tv[6]=(bf16_t)f1.z; tv[7]=(bf16_t)f1.w;
    } else {
#pragma unroll
      for (int j = 0; j < 8; ++j) tv[j] = (bf16_t)0.f;
    }
    *(bf16x8*)(dst + r * TP + off) = tv;
  }
}

// one K=128 MFMA pass: A from LDS (wave-private 32 rows), B-frags streamed from global WF chunk
__device__ __forceinline__ void mfma_gk128(const bf16_t* A, const bf16_t* __restrict__ Wf,
                                           int w, int lane, int lm, int lq, f32x4 acc[2][8]) {
#pragma unroll
  for (int kk = 0; kk < 4; ++kk) {
    int ko = kk * 32 + lq * 8;
    bf16x8 a0 = *(const bf16x8*)(A + (w * 32 + lm) * TP + ko);
    bf16x8 a1 = *(const bf16x8*)(A + (w * 32 + 16 + lm) * TP + ko);
    const bf16_t* wp = Wf + ((kk * 8) << 9) + (lane << 3);
#pragma unroll
    for (int ct = 0; ct < 8; ++ct) {
      bf16x8 bfr = *(const bf16x8*)(wp + (ct << 9));
      acc[0][ct] = __builtin_amdgcn_mfma_f32_16x16x32_bf16(a0, bfr, acc[0][ct], 0, 0, 0);
      acc[1][ct] = __builtin_amdgcn_mfma_f32_16x16x32_bf16(a1, bfr, acc[1][ct], 0, 0, 0);
    }
  }
}

// online-softmax merge over 2^k lanes (seg-style), state (m,s)
__device__ __forceinline__ void merge_shfl(float& m, float& s, int width) {
  for (int k = 1; k < width; k <<= 1) {
    float m2 = __shfl_xor(m, k), s2 = __shfl_xor(s, k);
    float M = fmaxf(m, m2), ns = 0.f;
    if (m  > -1e29f) ns += s  * expf(m  - M);
    if (m2 > -1e29f) ns += s2 * expf(m2 - M);
    m = M; s = ns;
  }
}

// ---------------- prep kernels ----------------
__global__ void gn_xcvt(const float* x, bf16_t* xb) {
  int i = blockIdx.x * 256 + threadIdx.x;
  if (i < N_NODES * DIM / 4) {
    float4 f = ((const float4*)x)[i];
    bf16x4 o; o[0]=(bf16_t)f.x; o[1]=(bf16_t)f.y; o[2]=(bf16_t)f.z; o[3]=(bf16_t)f.w;
    *(bf16x4*)(xb + (size_t)i * 4) = o;
  }
}

// build b-frag-layout bf16 weights from f32 sources. 13 chunks of 16384 elems.
__global__ void gn_fragw(const float* We1, const float* We2, const float* Wm1, const float* Wm2,
                         const float* Wu1, const float* Wu2, const float* Wk, const float* Wv,
                         bf16_t* WF) {
  int idx = blockIdx.x * 256 + threadIdx.x;
  if (idx >= WF_ELEMS) return;
  int seg = idx >> 14;
  const float* W; int kc;
  switch (seg) {
    case 0:  W = We1; kc = 0; break;
    case 1:  W = We1; kc = 1; break;
    case 2:  W = We1; kc = 2; break;
    case 3:  W = We2; kc = 0; break;
    case 4:  W = Wm1; kc = 0; break;
    case 5:  W = Wm1; kc = 1; break;
    case 6:  W = Wm2; kc = 0; break;
    case 7:  W = Wu1; kc = 0; break;
    case 8:  W = Wu1; kc = 1; break;
    case 9:  W = Wu1; kc = 2; break;
    case 10: W = Wu2; kc = 0; break;
    case 11: W = Wk;  kc = 0; break;
    default: W = Wv;  kc = 0; break;
  }
  int r = idx & 16383;
  int j = r & 7, lane = (r >> 3) & 63, ct = (r >> 9) & 7, kk = (r >> 12) & 3;
  int k = kc * 128 + kk * 32 + (lane >> 4) * 8 + j;
  int n = ct * 16 + (lane & 15);
  WF[idx] = (bf16_t)W[k * 128 + n];
}

// R = u @ W_e1[384:512] + b_e1 ; uw = u @ W_w[128:256] + b_w
__global__ void gn_uprep(const float* u, const float* We1, const float* be1,
                         const float* Ww, const float* bw, float* R, float* uw) {
  int t = threadIdx.x;
  for (int idx = blockIdx.x * 256 + t; idx < 32 * 128; idx += gridDim.x * 256) {
    int g = idx >> 7, c = idx & 127;
    float acc = be1[c];
    for (int k = 0; k < 128; ++k) acc += u[g * 128 + k] * We1[(384 + k) * 128 + c];
    R[idx] = acc;
  }
  if (blockIdx.x == 0 && t < 32) {
    float acc = bw[0];
    for (int k = 0; k < 128; ++k) acc += u[t * 128 + k] * Ww[128 + k];
    uw[t] = acc;
  }
}

__global__ void gn_count(const int* ei, float* cnt) {
  int e = blockIdx.x * 256 + threadIdx.x;
  if (e < NEDGE) atomicAdd(&cnt[ei[NEDGE + e]], 1.0f);
}

__global__ void gn_q(const float* qa, const float* Wq, const float* bq, float* qb) {
  int b = blockIdx.x, t = threadIdx.x;
  int c = t & 127, half = t >> 7;
  const float* qrow = qa + b * 1024 + half * 512;
  float acc = 0.f;
  for (int k = 0; k < 512; ++k) acc += qrow[k] * Wq[(half * 512 + k) * 128 + c];
  __shared__ float red[256];
  red[t] = acc;
  __syncthreads();
  if (half == 0) qb[b * 128 + c] = red[c] + red[128 + c] + bq[c];
}

// layer-0 wt logits from f32 ea; also materialize edge_batch GB
__global__ void gn_wl0(const float* ea, const float* Ww, const float* uw,
                       const int* ei, const int* nbat, float* wl, int* gb) {
  int t = threadIdx.x;
  int sub = t & 15, grp = t >> 4;
  for (int e = blockIdx.x * 16 + grp; e < NEDGE; e += gridDim.x * 16) {
    const float* er = ea + (size_t)e * DIM + sub * 8;
    float s = 0.f;
#pragma unroll
    for (int j = 0; j < 8; ++j) s += er[j] * Ww[sub * 8 + j];
#pragma unroll
    for (int m = 1; m < 16; m <<= 1) s += __shfl_xor(s, m);
    if (sub == 0) {
      int g = nbat[ei[e]];
      wl[e] = s + uw[g];
      gb[e] = g;
    }
  }
}

// per-128-edge-block softmax partials for layer 0 (fused kernel emits these for later layers)
__global__ void gn_part0(const float* wl, const int* gb, float* pm, float* ps) {
  __shared__ float lv[128];
  __shared__ int   lgg[128];
  int t = threadIdx.x, blk = blockIdx.x, e0 = blk * 128;
  if (t < 128) { lv[t] = wl[e0 + t]; lgg[t] = gb[e0 + t]; }
  __syncthreads();
  int g = t >> 3, seg = t & 7;
  float m = -1e30f, s = 0.f;
  for (int i = seg * 16; i < seg * 16 + 16; ++i)
    if (lgg[i] == g) {
      float v = lv[i];
      if (v > m) { s = s * expf(m - v) + 1.f; m = v; }
      else s += expf(v - m);
    }
  merge_shfl(m, s, 8);
  if (seg == 0) { pm[blk * 32 + g] = m; ps[blk * 32 + g] = s; }
}

__global__ void gn_reduce_ms(const float* pm, const float* ps, float* mg, float* sg, int nb) {
  int g = blockIdx.x, t = threadIdx.x;
  __shared__ float red[256];
  float m = -1e30f;
  for (int i = t; i < nb; i += 256) m = fmaxf(m, pm[i * 32 + g]);
  red[t] = m; __syncthreads();
  for (int s2 = 128; s2 > 0; s2 >>= 1) { if (t < s2) red[t] = fmaxf(red[t], red[t + s2]); __syncthreads(); }
  m = red[0]; __syncthreads();
  float s = 0.f;
  for (int i = t; i < nb; i += 256) {
    float sb = ps[i * 32 + g];
    if (sb > 0.f) s += sb * expf(pm[i * 32 + g] - m);
  }
  red[t] = s; __syncthreads();
  for (int s2 = 128; s2 > 0; s2 >>= 1) { if (t < s2) red[t] += red[t + s2]; __syncthreads(); }
  if (t == 0) { mg[g] = m; sg[g] = red[0]; }
}

// ---------------- fused edge+message kernel ----------------
// computes new edge_attr (EB), scatters weighted messages into recv,
// and emits next-layer wt logits + per-block softmax partials.
__global__ __launch_bounds__(256, 2) void gn_fused(
    const bf16_t* __restrict__ xb,      // bf16 node features (XB0 layer0, XB after)
    const void* esrcv, int efirst,      // old edge_attr: f32 ea (layer0) or bf16 EB
    bf16_t* edst,
    const bf16_t* __restrict__ WF,
    const float* R, const float* UW, const float* Wwv,
    const float* be2, const float* bm1, const float* bm2,
    const float* wl_cur, const float* mg, const float* sg,
    float* wl_next, float* pm, float* ps, int last,
    const int* ei, const int* gb, float* recv) {
  __shared__ bf16_t sA[128 * TP];
  __shared__ int lrow[128], lcol[128], lg[128];
  __shared__ float lwt[128], lnw[128];

  int t = threadIdx.x, blk = blockIdx.x;
  int e0 = blk * 128;
  int w = t >> 6, lane = t & 63, lm = lane & 15, lq = lane >> 4;

  if (t < 128) {
    int e = e0 + t;
    lrow[t] = ei[e];
    lcol[t] = ei[NEDGE + e];
    int g = gb[e];
    lg[t] = g;
    lnw[t] = expf(wl_cur[e] - mg[g]) / sg[g];
  }
  __syncthreads();                       // (1)

  f32x4 accE[2][8], accM[2][8];
  acc_zero(accE);
  acc_zero(accM);

  // chunk: x[row] -> both E1c0 and M1c0
  stage_rows_bf(sA, xb, lrow, t);
  __syncthreads();                       // (2)
  mfma_gk128(sA, WF + FE1, w, lane, lm, lq, accE);
  mfma_gk128(sA, WF + FM1, w, lane, lm, lq, accM);
  __syncthreads();                       // (3)
  // chunk: x[col] -> E1c1
  stage_rows_bf(sA, xb, lcol, t);
  __syncthreads();                       // (4)
  mfma_gk128(sA, WF + FE1 + 16384, w, lane, lm, lq, accE);
  __syncthreads();                       // (5)
  // chunk: old edge_attr -> E1c2
  if (efirst) stage_seq_f32(sA, (const float*)esrcv, e0, 128, t);
  else        stage_seq_bf (sA, (const bf16_t*)esrcv, e0, 128, t);
  __syncthreads();                       // (6)
  mfma_gk128(sA, WF + FE1 + 32768, w, lane, lm, lq, accE);
  __syncthreads();                       // (7)

  // epi1: hidden_e = relu(accE + R[g])
#pragma unroll
  for (int rt = 0; rt < 2; ++rt)
#pragma unroll
    for (int reg = 0; reg < 4; ++reg) {
      int row = w * 32 + rt * 16 + lq * 4 + reg;
      const float* Rr = R + (size_t)lg[row] * DIM;
#pragma unroll
      for (int ct = 0; ct < 8; ++ct) {
        int col = ct * 16 + lm;
        sA[row * TP + col] = (bf16_t)fmaxf(accE[rt][ct][reg] + Rr[col], 0.f);
      }
    }
  __syncthreads();                       // (8)
  acc_zero(accE);
  mfma_gk128(sA, WF + FE2, w, lane, lm, lq, accE);
  __syncthreads();                       // (9)

  // epi2: new_edge = accE + be2 -> EB (global) + sA (for M1c1) + next-layer logits
  {
    float ww8[8], be8[8];
#pragma unroll
    for (int ct = 0; ct < 8; ++ct) { ww8[ct] = Wwv[ct * 16 + lm]; be8[ct] = be2[ct * 16 + lm]; }
#pragma unroll
    for (int rt = 0; rt < 2; ++rt)
#pragma unroll
      for (int reg = 0; reg < 4; ++reg) {
        int row = w * 32 + rt * 16 + lq * 4 + reg;
        bf16_t* drow = edst + (size_t)(e0 + row) * DIM;
        float lsum = 0.f;
#pragma unroll
        for (int ct = 0; ct < 8; ++ct) {
          int col = ct * 16 + lm;
          float v = accE[rt][ct][reg] + be8[ct];
          drow[col] = (bf16_t)v;
          sA[row * TP + col] = (bf16_t)v;
          lsum += v * ww8[ct];
        }
        if (!last) {
          // reduce lsum across the 16 lm lanes (same lq)
          lsum += __shfl_xor(lsum, 1);
          lsum += __shfl_xor(lsum, 2);
          lsum += __shfl_xor(lsum, 4);
          lsum += __shfl_xor(lsum, 8);
          if (lm == 0) {
            float v = lsum + UW[lg[row]];
            wl_next[e0 + row] = v;
            lwt[row] = v;
          }
        }
      }
  }
  __syncthreads();                       // (10)
  mfma_gk128(sA, WF + FM1 + 16384, w, lane, lm, lq, accM);
  __syncthreads();                       // (11)

  // epi3: hidden_m = relu(accM + bm1)
#pragma unroll
  for (int rt = 0; rt < 2; ++rt)
#pragma unroll
    for (int reg = 0; reg < 4; ++reg) {
      int row = w * 32 + rt * 16 + lq * 4 + reg;
#pragma unroll
      for (int ct = 0; ct < 8; ++ct) {
        int col = ct * 16 + lm;
        sA[row * TP + col] = (bf16_t)fmaxf(accM[rt][ct][reg] + bm1[col], 0.f);
      }
    }
  __syncthreads();                       // (12)
  acc_zero(accM);
  mfma_gk128(sA, WF + FM2, w, lane, lm, lq, accM);

  // epi4: scatter msg * norm_w into recv[col]
#pragma unroll
  for (int rt = 0; rt < 2; ++rt)
#pragma unroll
    for (int reg = 0; reg < 4; ++reg) {
      int row = w * 32 + rt * 16 + lq * 4 + reg;
      float nwv = lnw[row];
      float* rr = recv + (size_t)lcol[row] * DIM;
#pragma unroll
      for (int ct = 0; ct < 8; ++ct) {
        int col = ct * 16 + lm;
        atomicAdd(&rr[col], (accM[rt][ct][reg] + bm2[col]) * nwv);
      }
    }

  // per-block softmax partials for next layer (parallel: 8 threads/graph)
  if (!last) {
    int g = t >> 3, seg = t & 7;
    float m = -1e30f, s = 0.f;
    for (int i = seg * 16; i < seg * 16 + 16; ++i)
      if (lg[i] == g) {
        float v = lwt[i];
        if (v > m) { s = s * expf(m - v) + 1.f; m = v; }
        else s += expf(v - m);
      }
    merge_shfl(m, s, 8);
    if (seg == 0) { pm[blk * 32 + g] = m; ps[blk * 32 + g] = s; }
  }
}

// ---------------- node update kernel ----------------
__global__ __launch_bounds__(256) void gn_node(
    const bf16_t* xsrc, bf16_t* xdst, const float* recv, const float* cnt,
    const float* u, const bf16_t* __restrict__ WF,
    const float* bu1, const float* bu2, const int* nbat) {
  __shared__ bf16_t sA[128 * TP];
  __shared__ int lg[128];

  int t = threadIdx.x;
  int n0 = blockIdx.x * 128;
  int nvalid = N_NODES - n0; if (nvalid > 128) nvalid = 128;
  int w = t >> 6, lane = t & 63, lm = lane & 15, lq = lane >> 4;

  if (t < 128) lg[t] = (t < nvalid) ? nbat[n0 + t] : 0;
  __syncthreads();

  f32x4 acc[2][8];
  acc_zero(acc);

  stage_seq_bf(sA, xsrc, n0, nvalid, t);
  __syncthreads();
  mfma_gk128(sA, WF + FU1, w, lane, lm, lq, acc);
  __syncthreads();
  // received = recv / max(cnt,1)
#pragma unroll
  for (int i = 0; i < 8; ++i) {
    int c = t + i * 256;
    int r = c >> 4, off = (c & 15) * 8;
    bf16x8 tv;
    if (r < nvalid) {
      const float* rr = recv + (size_t)(n0 + r) * DIM + off;
      float ic = 1.f / fmaxf(cnt[n0 + r], 1.f);
#pragma unroll
      for (int j = 0; j < 8; ++j) tv[j] = (bf16_t)(rr[j] * ic);
    } else {
#pragma unroll
      for (int j = 0; j < 8; ++j) tv[j] = (bf16_t)0.f;
    }
    *(bf16x8*)(sA + r * TP + off) = tv;
  }
  __syncthreads();
  mfma_gk128(sA, WF + FU1 + 16384, w, lane, lm, lq, acc);
  __syncthreads();
  stage_rows_f32(sA, u, lg, t);
  __syncthreads();
  mfma_gk128(sA, WF + FU1 + 32768, w, lane, lm, lq, acc);
  __syncthreads();

#pragma unroll
  for (int rt = 0; rt < 2; ++rt)
#pragma unroll
    for (int reg = 0; reg < 4; ++reg) {
      int row = w * 32 + rt * 16 + lq * 4 + reg;
#pragma unroll
      for (int ct = 0; ct < 8; ++ct) {
        int col = ct * 16 + lm;
        sA[row * TP + col] = (bf16_t)fmaxf(acc[rt][ct][reg] + bu1[col], 0.f);
      }
    }
  __syncthreads();
  acc_zero(acc);
  mfma_gk128(sA, WF + FU2, w, lane, lm, lq, acc);

#pragma unroll
  for (int rt = 0; rt < 2; ++rt)
#pragma unroll
    for (int reg = 0; reg < 4; ++reg) {
      int row = w * 32 + rt * 16 + lq * 4 + reg;
      if (row < nvalid) {
        bf16_t* dr = xdst + (size_t)(n0 + row) * DIM;
#pragma unroll
        for (int ct = 0; ct < 8; ++ct) {
          int col = ct * 16 + lm;
          dr[col] = (bf16_t)(acc[rt][ct][reg] + bu2[col]);
        }
      }
    }
}

// ---------------- evidence -> K/V projection ----------------
__global__ __launch_bounds__(256) void gn_ev(
    const bf16_t* xsrc, const bf16_t* __restrict__ WF,
    const float* bk, const float* bv, float* kb, float* vb) {
  __shared__ bf16_t sA[128 * TP];

  int t = threadIdx.x;
  int n0 = blockIdx.x * 128;
  int nvalid = N_NODES - n0; if (nvalid > 128) nvalid = 128;
  int sel = blockIdx.y;
  const bf16_t* Wf = WF + (sel ? FV : FK);
  const float* bias = sel ? bv : bk;
  float* dst = sel ? vb : kb;
  int w = t >> 6, lane = t & 63, lm = lane & 15, lq = lane >> 4;

#pragma unroll
  for (int i = 0; i < 8; ++i) {
    int c = t + i * 256;
    int r = c >> 4, off = (c & 15) * 8;
    bf16x8 tv;
    if (r < nvalid) {
      uint4 v = *(const uint4*)(xsrc + (size_t)(n0 + r) * DIM + off);
      bf16_t tmp[8];
      *(uint4*)tmp = v;
#pragma unroll
      for (int j = 0; j < 8; ++j) {
        float f = (float)tmp[j];
        tv[j] = (bf16_t)(0.5f * f * (1.f + erff(f * 0.70710678118654752f)));
      }
    } else {
#pragma unroll
      for (int j = 0; j < 8; ++j) tv[j] = (bf16_t)0.f;
    }
    *(bf16x8*)(sA + r * TP + off) = tv;
  }
  __syncthreads();

  f32x4 acc[2][8];
  acc_zero(acc);
  mfma_gk128(sA, Wf, w, lane, lm, lq, acc);

#pragma unroll
  for (int rt = 0; rt < 2; ++rt)
#pragma unroll
    for (int reg = 0; reg < 4; ++reg) {
      int row = w * 32 + rt * 16 + lq * 4 + reg;
      if (row < nvalid) {
        float* dr = dst + (size_t)(n0 + row) * DIM;
#pragma unroll
        for (int ct = 0; ct < 8; ++ct) {
          int col = ct * 16 + lm;
          dr[col] = acc[rt][ct][reg] + bias[col];
        }
      }
    }
}

// ---------------- pooled edge (final layer; wave-per-edge) ----------------
__global__ void gn_pooled_edge(const bf16_t* eb, const float* wl, const float* mg, const float* sg,
                               const int* gb, float* pe) {
  __shared__ float loc[4096];
  int t = threadIdx.x;
  for (int i = t; i < 4096; i += 256) loc[i] = 0.f;
  __syncthreads();
  int lane = t & 63, w = t >> 6;
  int wid = blockIdx.x * 4 + w, nw = gridDim.x * 4;
  for (int e = wid; e < NEDGE; e += nw) {
    int g = gb[e];
    float nwt = expf(wl[e] - mg[g]) / sg[g];
    const bf16_t* er = eb + (size_t)e * DIM + lane * 2;
    atomicAdd(&loc[g * 128 + lane * 2],     (float)er[0] * nwt);
    atomicAdd(&loc[g * 128 + lane * 2 + 1], (float)er[1] * nwt);
  }
  __syncthreads();
  for (int i = t; i < 4096; i += 256) atomicAdd(&pe[i], loc[i]);
}

// ---------------- attention pool ----------------
__global__ void gn_att(const float* qb, const float* kb, const float* vb, const int* non, float* out) {
  int b = blockIdx.x >> 1, h = blockIdx.x & 1, t = threadIdx.x;
  __shared__ float qv[64];
  __shared__ float sc[625];
  __shared__ float red[256];
  if (t < 64) qv[t] = qb[b * 128 + h * 64 + t];
  __syncthreads();
  int nn = non[b];
  for (int l = t; l < 625; l += 256) {
    float acc = 0.f;
    const float* kr = kb + ((size_t)(b * 625 + l)) * DIM + h * 64;
    for (int d2 = 0; d2 < 64; ++d2) acc += qv[d2] * kr[d2];
    sc[l] = (l < nn) ? acc * 0.125f : -1e30f;
  }
  __syncthreads();
  float m = -1e30f;
  for (int l = t; l < 625; l += 256) m = fmaxf(m, sc[l]);
  red[t] = m; __syncthreads();
  for (int s2 = 128; s2 > 0; s2 >>= 1) { if (t < s2) red[t] = fmaxf(red[t], red[t + s2]); __syncthreads(); }
  m = red[0]; __syncthreads();
  float ssum = 0.f;
  for (int l = t; l < 625; l += 256) { float e = expf(sc[l] - m); sc[l] = e; ssum += e; }
  red[t] = ssum; __syncthreads();
  for (int s2 = 128; s2 > 0; s2 >>= 1) { if (t < s2) red[t] += red[t + s2]; __syncthreads(); }
  float inv = 1.f / red[0];
  __syncthreads();
  int d = t & 63, seg = t >> 6;
  float acc = 0.f;
  for (int l = seg; l < 625; l += 4) acc += sc[l] * vb[((size_t)(b * 625 + l)) * DIM + h * 64 + d];
  red[t] = acc; __syncthreads();
  if (t < 64) {
    float v = red[t] + red[64 + t] + red[128 + t] + red[192 + t];
    out[b * 256 + 128 + h * 64 + d] = v * inv;
  }
}

__global__ void gn_fin(const float* pe, float* out) {
  int t = threadIdx.x;
  for (int i = t; i < 4096; i += 256) {
    int b = i >> 7, c = i & 127;
    out[b * 256 + c] = pe[i];
  }
}

// ---------------- launcher ----------------
extern "C" void kernel_launch(void* const* d_in, const int* in_sizes, int n_in,
                              void* d_out, int out_size, void* d_ws, size_t ws_size,
                              hipStream_t stream) {
  const float* x   = (const float*)d_in[0];
  const float* ea  = (const float*)d_in[1];
  const float* u   = (const float*)d_in[2];
  const float* qa  = (const float*)d_in[3];
  const float* We1 = (const float*)d_in[4];
  const float* be1 = (const float*)d_in[5];
  const float* We2 = (const float*)d_in[6];
  const float* be2 = (const float*)d_in[7];
  const float* Ww  = (const float*)d_in[8];
  const float* bw  = (const float*)d_in[9];
  const float* Wm1 = (const float*)d_in[10];
  const float* bm1 = (const float*)d_in[11];
  const float* Wm2 = (const float*)d_in[12];
  const float* bm2 = (const float*)d_in[13];
  const float* Wu1 = (const float*)d_in[14];
  const float* bu1 = (const float*)d_in[15];
  const float* Wu2 = (const float*)d_in[16];
  const float* bu2 = (const float*)d_in[17];
  const float* Wq  = (const float*)d_in[18];
  const float* bq  = (const float*)d_in[19];
  const float* Wk  = (const float*)d_in[20];
  const float* bk  = (const float*)d_in[21];
  const float* Wv  = (const float*)d_in[22];
  const float* bv  = (const float*)d_in[23];
  const int* ei   = (const int*)d_in[24];
  const int* nbat = (const int*)d_in[25];
  const int* non  = (const int*)d_in[26];
  float* out = (float*)d_out;

  char* p = (char*)d_ws;
  auto alloc = [&](size_t bytes) { char* r = p; p += (bytes + 255) & ~(size_t)255; return r; };
  bf16_t* EB  = (bf16_t*)alloc((size_t)NEDGE * DIM * 2);
  bf16_t* XB  = (bf16_t*)alloc((size_t)N_NODES * DIM * 2);
  bf16_t* XB0 = (bf16_t*)alloc((size_t)N_NODES * DIM * 2);
  float* RECV = (float*)alloc((size_t)N_NODES * DIM * 4);
  float* CNT  = (float*)alloc((size_t)N_NODES * 4);
  float* WL   = (float*)alloc((size_t)NEDGE * 4);
  float* WLn  = (float*)alloc((size_t)NEDGE * 4);
  int*   GB   = (int*)alloc((size_t)NEDGE * 4);
  float* PM   = (float*)alloc((size_t)EBLK * 32 * 4);
  float* PS   = (float*)alloc((size_t)EBLK * 32 * 4);
  float* MG   = (float*)alloc(32 * 4);
  float* SG   = (float*)alloc(32 * 4);
  float* R    = (float*)alloc(32 * 128 * 4);
  float* UW   = (float*)alloc(32 * 4);
  bf16_t* WF  = (bf16_t*)alloc((size_t)WF_ELEMS * 2);
  float* QB   = (float*)alloc(32 * 128 * 4);
  float* KB   = (float*)alloc((size_t)N_NODES * DIM * 4);
  float* VB   = (float*)alloc((size_t)N_NODES * DIM * 4);
  float* PE   = (float*)alloc(32 * 128 * 4);

  hipMemsetAsync(CNT, 0, (size_t)N_NODES * 4, stream);
  hipMemsetAsync(PE, 0, 32 * 128 * 4, stream);

  gn_xcvt<<<(N_NODES * DIM / 4 + 255) / 256, 256, 0, stream>>>(x, XB0);
  gn_fragw<<<(WF_ELEMS + 255) / 256, 256, 0, stream>>>(We1, We2, Wm1, Wm2, Wu1, Wu2, Wk, Wv, WF);
  gn_uprep<<<16, 256, 0, stream>>>(u, We1, be1, Ww, bw, R, UW);
  gn_count<<<1250, 256, 0, stream>>>(ei, CNT);
  gn_q<<<32, 256, 0, stream>>>(qa, Wq, bq, QB);
  gn_wl0<<<2500, 256, 0, stream>>>(ea, Ww, UW, ei, nbat, WL, GB);
  gn_part0<<<EBLK, 256, 0, stream>>>(WL, GB, PM, PS);

  for (int layer = 0; layer < 3; ++layer) {
    int first = (layer == 0) ? 1 : 0;
    int last = (layer == 2) ? 1 : 0;
    const bf16_t* xs = first ? XB0 : XB;
    const void* es = first ? (const void*)ea : (const void*)EB;
    float* cur = (layer == 1) ? WLn : WL;
    float* nxt = (layer == 1) ? WL : WLn;
    gn_reduce_ms<<<32, 256, 0, stream>>>(PM, PS, MG, SG, EBLK);
    hipMemsetAsync(RECV, 0, (size_t)N_NODES * DIM * 4, stream);
    gn_fused<<<EBLK, 256, 0, stream>>>(xs, es, first, EB, WF, R, UW, Ww,
                                       be2, bm1, bm2, cur, MG, SG,
                                       nxt, PM, PS, last, ei, GB, RECV);
    gn_node<<<157, 256, 0, stream>>>(xs, XB, RECV, CNT, u, WF, bu1, bu2, nbat);
  }

  gn_pooled_edge<<<256, 256, 0, stream>>>(EB, WL, MG, SG, GB, PE);
  gn_ev<<<dim3(157, 2), 256, 0, stream>>>(XB, WF, bk, bv, KB, VB);
  gn_att<<<64, 256, 0, stream>>>(QB, KB, VB, non, out);
  gn_fin<<<1, 256, 0, stream>>>(PE, out);
}